// Round 2
// baseline (185.253 us; speedup 1.0000x reference)
//
#include <hip/hip_runtime.h>
#include <math.h>

#define L_TOTAL 65536
#define D_DIM   256
#define C_ROWS  32                    // rows per chunk
#define N_CHUNK (L_TOTAL / C_ROWS)    // 2048
#define SUPER   32                    // chunks per super-chunk
#define N_SUPER (N_CHUNK / SUPER)     // 64

typedef float vf4 __attribute__((ext_vector_type(4)));

// ---------------- kA: per-chunk aggregates, fully float4 -------------------
// Layout: wave w owns rows [8w, 8w+8); lane l owns cols [4l, 4l+4).
__global__ __launch_bounds__(256) void kA_aggregate(
    const float* __restrict__ K, const float* __restrict__ V,
    const float* __restrict__ q,
    float* __restrict__ s_g, float* __restrict__ cm,
    float* __restrict__ cu, float* __restrict__ cw)
{
    const int t = threadIdx.x;
    const int c = blockIdx.x;
    const int r0 = c * C_ROWS;
    const int wave = t >> 6, lane = t & 63;

    __shared__ float s_lds[C_ROWS];
    __shared__ vf4  pw_lds[4][64];    // 4 KB partial-w

    // V first (keep it LLC-resident for kF): 8 vf4 per thread
    vf4 v4[8];
    const vf4* Vp = reinterpret_cast<const vf4*>(V + (size_t)(r0 + wave * 8) * D_DIM) + lane;
    #pragma unroll
    for (int k = 0; k < 8; ++k) v4[k] = Vp[(size_t)k * (D_DIM / 4)];

    // K: streamed once -> non-temporal vf4, dot with q, wave-reduce
    const vf4 q4 = *reinterpret_cast<const vf4*>(q + 4 * lane);
    const vf4* Kp = reinterpret_cast<const vf4*>(K + (size_t)(r0 + wave * 8) * D_DIM) + lane;
    #pragma unroll
    for (int k = 0; k < 8; ++k) {
        const vf4 kv = __builtin_nontemporal_load(Kp + (size_t)k * (D_DIM / 4));
        float d = kv.x * q4.x + kv.y * q4.y + kv.z * q4.z + kv.w * q4.w;
        #pragma unroll
        for (int off = 32; off > 0; off >>= 1) d += __shfl_xor(d, off, 64);
        if (lane == 0) s_lds[wave * 8 + k] = d;
    }
    __syncthreads();

    if (t < C_ROWS) s_g[r0 + t] = s_lds[t];

    float m_c = -INFINITY;
    #pragma unroll
    for (int j = 0; j < C_ROWS; ++j) m_c = fmaxf(m_c, s_lds[j]);
    float u_c = 0.f;
    #pragma unroll
    for (int j = 0; j < C_ROWS; ++j) u_c += __expf(s_lds[j] - m_c);

    // per-wave partial weighted sum over its 8 rows
    vf4 pw = {0.f, 0.f, 0.f, 0.f};
    #pragma unroll
    for (int k = 0; k < 8; ++k) {
        const float cf = __expf(s_lds[wave * 8 + k] - m_c);
        pw = pw + cf * v4[k];
    }
    pw_lds[wave][lane] = pw;
    __syncthreads();

    if (t < 64) {
        const vf4 w4 = (pw_lds[0][t] + pw_lds[1][t]) + (pw_lds[2][t] + pw_lds[3][t]);
        reinterpret_cast<vf4*>(cw + (size_t)c * D_DIM)[t] = w4;
    }
    if (t == 0) { cm[c] = m_c; cu[c] = u_c; }
}

// ---------------- kCB: redundant scalar scan + per-super vector scan -------
// (unchanged this round: only ~4 MB of traffic, not visible in the profile)
__global__ __launch_bounds__(256) void kCB_scan(
    const float* __restrict__ cm, const float* __restrict__ cu,
    const float* __restrict__ cw,
    float* __restrict__ pm, float* __restrict__ pu,
    float* __restrict__ gsup,
    float* __restrict__ pwl, float* __restrict__ T)
{
    const int t = threadIdx.x;
    const int S = blockIdx.x;
    __shared__ float Lm[256], Lu[256];
    __shared__ float pmL[N_CHUNK + 1];
    __shared__ float ca[SUPER], cb[SUPER];

    float am[8], au[8];
    float M = -INFINITY, U = 0.f;
    #pragma unroll
    for (int j = 0; j < 8; ++j) {
        am[j] = cm[8 * t + j]; au[j] = cu[8 * t + j];
        const float mm = fmaxf(M, am[j]);
        U = U * __expf(M - mm) + au[j] * __expf(am[j] - mm);
        M = mm;
    }
    Lm[t] = M; Lu[t] = U;
    float Mi = M, Ui = U;
    __syncthreads();
    for (int off = 1; off < 256; off <<= 1) {
        float m1 = 0.f, u1 = 0.f;
        const bool act = (t >= off);
        if (act) { m1 = Lm[t - off]; u1 = Lu[t - off]; }
        __syncthreads();
        if (act) {
            const float mm = fmaxf(m1, Mi);
            Ui = u1 * __expf(m1 - mm) + Ui * __expf(Mi - mm);
            Mi = mm;
            Lm[t] = Mi; Lu[t] = Ui;
        }
        __syncthreads();
    }
    float Me = (t == 0) ? -INFINITY : Lm[t - 1];
    float Ue = (t == 0) ? 0.f : Lu[t - 1];
    #pragma unroll
    for (int j = 0; j < 8; ++j) {
        pmL[8 * t + j] = Me;
        if (S == 0) { pm[8 * t + j] = Me; pu[8 * t + j] = Ue; }
        const float mm = fmaxf(Me, am[j]);
        Ue = Ue * __expf(Me - mm) + au[j] * __expf(am[j] - mm);
        Me = mm;
    }
    if (t == 255) {
        pmL[N_CHUNK] = Me;
        if (S == 0) { pm[N_CHUNK] = Me; pu[N_CHUNK] = Ue; }
    }
    __syncthreads();

    float wv[SUPER];
    const float* cwp = cw + (size_t)S * SUPER * D_DIM + t;
    #pragma unroll
    for (int j = 0; j < SUPER; ++j) wv[j] = cwp[(size_t)j * D_DIM];

    if (t < SUPER) {
        const int c = S * SUPER + t;
        ca[t] = __expf(pmL[c] - pmL[c + 1]);   // c=0: exp(-inf)=0
        cb[t] = __expf(cm[c] - pmL[c + 1]);
    }
    if (t == 0)
        gsup[S] = __expf(pmL[S * SUPER] - pmL[S * SUPER + SUPER]); // S=0: 0
    __syncthreads();

    float PW = 0.f;
    float* pwlp = pwl + (size_t)S * SUPER * D_DIM + t;
    #pragma unroll
    for (int j = 0; j < SUPER; ++j) {
        pwlp[(size_t)j * D_DIM] = PW;
        PW = PW * ca[j] + wv[j] * cb[j];
    }
    T[(size_t)S * D_DIM + t] = PW;
}

// ---------------- kF: float4 everywhere via 4-segment row scan -------------
// Layout: wave w owns rows [8w, 8w+8); lane l owns cols [4l, 4l+4).
// Wave 0: shuffle row-scan (sa/se/sri). Wave 1: vf4 cross-super seed.
// All waves: pass1 (zero-init segment scan) -> cross-wave combine -> pass2.
__global__ __launch_bounds__(256) void kF_output(
    const float* __restrict__ V, const float* __restrict__ s_g,
    const float* __restrict__ pm, const float* __restrict__ pu,
    const float* __restrict__ pwl, const float* __restrict__ T,
    const float* __restrict__ gsup,
    float* __restrict__ out)
{
    const int t = threadIdx.x;
    const int c = blockIdx.x;
    const int S = c / SUPER;
    const int r0 = c * C_ROWS;
    const int wave = t >> 6, lane = t & 63;

    __shared__ float sa[C_ROWS], se[C_ROWS], sri[C_ROWS];
    __shared__ vf4 seedL[64];       // 1 KB: cross-chunk seed per column-quad
    __shared__ vf4 seg[4][64];      // 4 KB: per-wave segment results
    __shared__ float asL[4];        // per-wave decay products

    // V: 8 vf4 per thread (independent, issued first)
    vf4 v4[8];
    const vf4* Vp = reinterpret_cast<const vf4*>(V + (size_t)(r0 + wave * 8) * D_DIM) + lane;
    #pragma unroll
    for (int k = 0; k < 8; ++k) v4[k] = Vp[(size_t)k * (D_DIM / 4)];

    if (wave == 0) {
        // barrier-free shuffle scan over the 32 rows
        const float pmc = pm[c];
        const float puc = pu[c];
        float s_val = -INFINITY;
        if (lane < C_ROWS) s_val = s_g[r0 + lane];
        float m = s_val, u = 1.0f;
        #pragma unroll
        for (int off = 1; off < C_ROWS; off <<= 1) {
            const float m1 = __shfl_up(m, off, 32);
            const float u1 = __shfl_up(u, off, 32);
            if ((lane & 31) >= off) {
                const float mm = fmaxf(m1, m);
                u = u1 * __expf(m1 - mm) + u * __expf(m - mm);
                m = mm;
            }
        }
        const float m_row = fmaxf(pmc, m);
        const float u_row = puc * __expf(pmc - m_row) + u * __expf(m - m_row);
        const float m_prev_raw = __shfl_up(m_row, 1, 32);
        const float m_prev = ((lane & 31) == 0) ? pmc : m_prev_raw;
        if (lane < C_ROWS) {
            sa[lane]  = __expf(m_prev - m_row);   // row0 of chunk0: exp(-inf)=0
            se[lane]  = __expf(s_val - m_row);
            sri[lane] = 1.0f / u_row;
        }
    } else if (wave == 1) {
        // cross-super exclusive vector prefix in vf4, published via LDS
        const float pmc = pm[c];
        const float pmS = pm[S * SUPER];
        vf4 SW = {0.f, 0.f, 0.f, 0.f};
        const vf4* T4 = reinterpret_cast<const vf4*>(T) + lane;
        #pragma unroll 8
        for (int Sp = 0; Sp < S; ++Sp) {
            const float g = gsup[Sp];
            SW = SW * g + T4[(size_t)Sp * (D_DIM / 4)];
        }
        const float gf = (c == 0) ? 0.f : __expf(pmS - pmc);
        const vf4 sp = reinterpret_cast<const vf4*>(pwl + (size_t)c * D_DIM)[lane];
        seedL[lane] = SW * gf + sp;
    }
    __syncthreads();   // sa/se/sri + seedL ready

    // pass 1: zero-init local segment scan over this wave's 8 rows
    vf4 B = {0.f, 0.f, 0.f, 0.f};
    float A = 1.f;
    #pragma unroll
    for (int k = 0; k < 8; ++k) {
        const int j = wave * 8 + k;
        B = B * sa[j] + v4[k] * se[j];
        A *= sa[j];
    }
    seg[wave][lane] = B;
    if (lane == 0) asL[wave] = A;
    __syncthreads();

    // cross-wave combine: exact serial fold of segment summaries
    vf4 W = seedL[lane];
    for (int p = 0; p < wave; ++p)
        W = W * asL[p] + seg[p][lane];

    // pass 2: final recurrence with correct W_in, vf4 NT stores
    float* Op = out + (size_t)(r0 + wave * 8) * D_DIM + 4 * lane;
    #pragma unroll
    for (int k = 0; k < 8; ++k) {
        const int j = wave * 8 + k;
        W = W * sa[j] + v4[k] * se[j];
        __builtin_nontemporal_store(W * sri[j],
                                    reinterpret_cast<vf4*>(Op + (size_t)k * D_DIM));
    }
}

extern "C" void kernel_launch(void* const* d_in, const int* in_sizes, int n_in,
                              void* d_out, int out_size, void* d_ws, size_t ws_size,
                              hipStream_t stream) {
    const float* K = (const float*)d_in[0];
    const float* V = (const float*)d_in[1];
    const float* q = (const float*)d_in[2];
    float* out = (float*)d_out;

    float* ws   = (float*)d_ws;
    float* s_g  = ws;                                  // 65536
    float* cm   = s_g + L_TOTAL;                       // 2048
    float* cu   = cm + N_CHUNK;                        // 2048
    float* pm   = cu + N_CHUNK;                        // 2049 (+pad)
    float* pu   = pm + (N_CHUNK + 16);                 // 2049 (+pad)
    float* gsup = pu + (N_CHUNK + 16);                 // 64 (+pad)
    float* cw   = gsup + 128;                          // 2048*256
    float* pwl  = cw + (size_t)N_CHUNK * D_DIM;        // 2048*256
    float* T    = pwl + (size_t)N_CHUNK * D_DIM;       // 64*256

    kA_aggregate<<<N_CHUNK, 256, 0, stream>>>(K, V, q, s_g, cm, cu, cw);
    kCB_scan<<<N_SUPER, 256, 0, stream>>>(cm, cu, cw, pm, pu, gsup, pwl, T);
    kF_output<<<N_CHUNK, 256, 0, stream>>>(V, s_g, pm, pu, pwl, T, gsup, out);
}